// Round 1
// baseline (118849.268 us; speedup 1.0000x reference)
//
#include <hip/hip_runtime.h>
#include <math.h>

// SocialLSTM on MI355X — round 1: persistent cooperative fp32 kernel.
// Structure: precompute ie[t] (input embedding) for all t in parallel,
// then one persistent kernel runs the 1024-step scan with 3 grid barriers
// per step (te | layer0 | layer1). Grid = 256 blocks (1/CU, forced by LDS).

#define NBLK 256
#define NTHR 256
#define SEQ  1024
#define HID  1024
#define EMB  512
#define NAG  21

// ws layout (float offsets)
#define IE_OFF   0
#define H0_OFF   11010048                    // SEQ*NAG*EMB
#define H1_OFF   (H0_OFF + 2*NAG*HID)
#define C0_OFF   (H1_OFF + 2*NAG*HID)
#define C1_OFF   (C0_OFF + NAG*HID)
#define TE_OFF   (C1_OFF + NAG*HID)
#define BAR_OFF  (TE_OFF + EMB)
#define ZTOT     (2*NAG*HID + 2*NAG*HID + NAG*HID + NAG*HID + EMB + 512)

struct Params {
  const float *x, *W_ie, *b_ie, *W_te, *b_te;
  const float *W_ih0, *W_hh0, *b_ih0, *b_hh0;
  const float *W_ih1, *W_hh1, *b_ih1, *b_hh1;
  const float *W_out, *b_out;
  float *out, *ws;
};

__device__ __forceinline__ float dot4(float4 a, float4 b) {
  return a.x*b.x + a.y*b.y + a.z*b.z + a.w*b.w;
}
__device__ __forceinline__ float sigf(float v) { return 1.0f / (1.0f + expf(-v)); }

__device__ __forceinline__ float block_sum(float v, float* red) {
  #pragma unroll
  for (int off = 32; off > 0; off >>= 1) v += __shfl_down(v, off, 64);
  const int w = threadIdx.x >> 6;
  if ((threadIdx.x & 63) == 0) red[w] = v;
  __syncthreads();
  float r = red[0] + red[1] + red[2] + red[3];
  __syncthreads();
  return r;
}

// 2-level tree barrier: 16 groups of 16 blocks -> root -> generation word.
// bars[0] = generation; bars[16 + g*16] = group-g counter; bars[16+256] = root.
// Counters are monotonic within a launch (init kernel zeroes each launch).
__device__ __forceinline__ void grid_barrier(unsigned* bars, unsigned ep, int b) {
  __syncthreads();
  if (threadIdx.x == 0) {
    __threadfence();  // release: publish this block's phase writes device-wide
    unsigned* gc = bars + 16 + ((unsigned)b >> 4) * 16;
    unsigned old = __hip_atomic_fetch_add(gc, 1u, __ATOMIC_RELAXED, __HIP_MEMORY_SCOPE_AGENT);
    if (old == ep * 16u - 1u) {
      unsigned rold = __hip_atomic_fetch_add(bars + 16 + 256, 1u, __ATOMIC_RELAXED, __HIP_MEMORY_SCOPE_AGENT);
      if (rold == ep * 16u - 1u)
        __hip_atomic_store(bars, ep, __ATOMIC_RELEASE, __HIP_MEMORY_SCOPE_AGENT);
    }
    while (__hip_atomic_load(bars, __ATOMIC_RELAXED, __HIP_MEMORY_SCOPE_AGENT) < ep)
      __builtin_amdgcn_s_sleep(2);
    __threadfence();  // acquire: invalidate so we see remote phase writes
  }
  __syncthreads();
}

__global__ void sl_init(float* ws) {
  int tid = blockIdx.x * blockDim.x + threadIdx.x;
  int stride = gridDim.x * blockDim.x;
  for (int i = tid; i < ZTOT; i += stride) ws[H0_OFF + i] = 0.0f;
}

// ie[t,a,e] = relu( sum_{k<43} x[t,k]*W_ie[e,k] + x[t,43+a]*W_ie[e,43] + b_ie[e] )
__global__ void sl_ie(const float* __restrict__ x, const float* __restrict__ W_ie,
                      const float* __restrict__ b_ie, float* __restrict__ ws) {
  const int t = blockIdx.x;
  const int tid = threadIdx.x;
  __shared__ float xs[64];
  __shared__ float base[EMB];
  __shared__ float w43[EMB];
  if (tid < 64) xs[tid] = x[t * 64 + tid];
  __syncthreads();
  for (int e = tid; e < EMB; e += NTHR) {
    const float* wr = W_ie + e * 44;
    float acc = b_ie[e];
    #pragma unroll
    for (int k = 0; k < 43; ++k) acc += xs[k] * wr[k];
    base[e] = acc;
    w43[e] = wr[43];
  }
  __syncthreads();
  float* iep = ws + IE_OFF + (size_t)t * (NAG * EMB);
  for (int idx = tid; idx < NAG * EMB; idx += NTHR) {
    int a = idx >> 9, e = idx & 511;
    float v = base[e] + xs[43 + a] * w43[e];
    iep[idx] = v > 0.0f ? v : 0.0f;
  }
}

__global__ void __launch_bounds__(NTHR, 1) sl_main(Params P) {
  const int b = blockIdx.x;
  const int tid = threadIdx.x;
  float* ws = P.ws;
  float* h0b = ws + H0_OFF;   // [2][21][1024] double-buffered
  float* h1b = ws + H1_OFF;
  float* c0  = ws + C0_OFF;   // [21][1024]
  float* c1  = ws + C1_OFF;
  float* te  = ws + TE_OFF;   // [512]
  unsigned* bars = (unsigned*)(ws + BAR_OFF);

  __shared__ float lds_h[NAG * 1028];   // h-state staging, stride 1028 (bank stagger)
  __shared__ float lds_ie[NAG * 516];   // ie_t staging, stride 516
  __shared__ float lds_te[EMB];
  __shared__ float part[6][84][4];      // K-split partial sums
  __shared__ float tepp[16][17];
  __shared__ float tep[16];             // te-part + biases per local gate row
  __shared__ float red[4];

  // K-loop mapping: tid -> (ks, gate, agent); 252 active threads
  const int ks  = tid / 84;
  const int rem = tid - ks * 84;
  const int ka  = rem % 21;     // agent
  const int krg = rem / 21;     // gate (0..3)
  const bool kact = (tid < 252);
  // finalize mapping: tid -> (agent, hloc); 84 active threads
  const int fa = tid % 21;
  const int fh = tid / 21;
  unsigned ep = 0;

  for (int t = 0; t < SEQ; ++t) {
    const int p = t & 1;
    const float* __restrict__ h1p = h1b + p * (NAG * HID);

    // ---------- phase A: te = relu(W_te @ h1p + b_te); block0: out[t-1] ----------
    {
      const float4* h4  = (const float4*)h1p;
      const float4* w04 = (const float4*)(P.W_te + (size_t)(2 * b) * (NAG * HID));
      const float4* w14 = (const float4*)(P.W_te + (size_t)(2 * b + 1) * (NAG * HID));
      const float4* wo4 = (const float4*)P.W_out;
      float a0 = 0.f, a1 = 0.f, a2 = 0.f;
      const bool do_out = (b == 0 && t > 0);
      for (int j = tid; j < (NAG * HID) / 4; j += NTHR) {
        float4 hv = h4[j];
        a0 += dot4(hv, w04[j]);
        a1 += dot4(hv, w14[j]);
        if (do_out) a2 += dot4(hv, wo4[j]);
      }
      a0 = block_sum(a0, red);
      a1 = block_sum(a1, red);
      if (do_out) {
        a2 = block_sum(a2, red);
        if (tid == 0) P.out[t - 1] = a2 + P.b_out[0];
      }
      if (tid == 0) {
        float v0 = a0 + P.b_te[2 * b];
        float v1 = a1 + P.b_te[2 * b + 1];
        te[2 * b]     = v0 > 0.f ? v0 : 0.f;
        te[2 * b + 1] = v1 > 0.f ? v1 : 0.f;
      }
    }
    ++ep; grid_barrier(bars, ep, b);

    // ---------- phase B: layer-0 cell; block b owns h cols [4b,4b+4) ----------
    {
      const float4* iep4 = (const float4*)(ws + IE_OFF + (size_t)t * (NAG * EMB));
      for (int i4 = tid; i4 < (NAG * EMB) / 4; i4 += NTHR) {
        int a = i4 >> 7, e4 = i4 & 127;
        *(float4*)&lds_ie[a * 516 + e4 * 4] = iep4[i4];
      }
      for (int i = tid; i < EMB; i += NTHR) lds_te[i] = te[i];
      const float4* h0p4 = (const float4*)(h0b + p * (NAG * HID));
      for (int i4 = tid; i4 < (NAG * HID) / 4; i4 += NTHR) {
        int a = i4 >> 8, k4 = i4 & 255;
        *(float4*)&lds_h[a * 1028 + k4 * 4] = h0p4[i4];
      }
      __syncthreads();
      // te-part (shared across agents) + biases -> tep[r]
      {
        int r = tid >> 4, l16 = tid & 15;
        int n = (r >> 2) * HID + b * 4 + (r & 3);
        const float* wtp = P.W_ih0 + (size_t)n * HID + EMB;
        float acc = 0.f;
        int e0 = l16 * 32;
        #pragma unroll
        for (int e = 0; e < 32; e += 4) {
          float4 tv = *(float4*)&lds_te[e0 + e];
          float4 wv = *(const float4*)&wtp[e0 + e];
          acc += dot4(tv, wv);
        }
        tepp[r][l16] = acc;
      }
      __syncthreads();
      if (tid < 16) {
        int n = (tid >> 2) * HID + b * 4 + (tid & 3);
        float s = P.b_ih0[n] + P.b_hh0[n];
        #pragma unroll
        for (int i = 0; i < 16; ++i) s += tepp[tid][i];
        tep[tid] = s;
      }
      // main K loop: ks=0 -> ie·W_ih0[:, :512]; ks=1,2 -> h0p·W_hh0 halves
      if (kact) {
        const float* zsrc = (ks == 0) ? (lds_ie + ka * 516)
                                      : (lds_h + ka * 1028 + (ks - 1) * EMB);
        const size_t nb = (size_t)(krg * HID + b * 4);
        const float* base = (ks == 0) ? (P.W_ih0 + nb * HID)
                                      : (P.W_hh0 + nb * HID + (size_t)(ks - 1) * EMB);
        const float4* w0p = (const float4*)base;
        const float4* w1p = (const float4*)(base + HID);
        const float4* w2p = (const float4*)(base + 2 * HID);
        const float4* w3p = (const float4*)(base + 3 * HID);
        float ac0 = 0.f, ac1 = 0.f, ac2 = 0.f, ac3 = 0.f;
        #pragma unroll 4
        for (int k4 = 0; k4 < EMB / 4; ++k4) {
          float4 z = *(const float4*)(zsrc + 4 * k4);
          ac0 += dot4(z, w0p[k4]);
          ac1 += dot4(z, w1p[k4]);
          ac2 += dot4(z, w2p[k4]);
          ac3 += dot4(z, w3p[k4]);
        }
        part[ks][rem][0] = ac0; part[ks][rem][1] = ac1;
        part[ks][rem][2] = ac2; part[ks][rem][3] = ac3;
      }
      __syncthreads();
      if (tid < 84) {
        float g4[4];
        #pragma unroll
        for (int g = 0; g < 4; ++g) {
          float v = tep[g * 4 + fh];
          v += part[0][g * 21 + fa][fh] + part[1][g * 21 + fa][fh] + part[2][g * 21 + fa][fh];
          g4[g] = v;
        }
        int idx = fa * HID + b * 4 + fh;
        float si = sigf(g4[0]), sf = sigf(g4[1]), so = sigf(g4[3]);
        float cn = sf * c0[idx] + si * tanhf(g4[2]);
        float hn = so * tanhf(cn);
        c0[idx] = cn;
        h0b[(p ^ 1) * (NAG * HID) + idx] = hn;
      }
    }
    ++ep; grid_barrier(bars, ep, b);

    // ---------- phase C: layer-1 cell (two LDS passes: h0n then h1p) ----------
    {
      const float4* s4 = (const float4*)(h0b + (p ^ 1) * (NAG * HID));
      for (int i4 = tid; i4 < (NAG * HID) / 4; i4 += NTHR) {
        int a = i4 >> 8, k4 = i4 & 255;
        *(float4*)&lds_h[a * 1028 + k4 * 4] = s4[i4];
      }
      __syncthreads();
      const int kst = ks * 344;
      const int ken = (kst + 344 < 1024) ? kst + 344 : 1024;
      if (kact) {
        const size_t nb = (size_t)(krg * HID + b * 4);
        const float* base = P.W_ih1 + nb * HID;
        const float* zs = lds_h + ka * 1028;
        float ac0 = 0.f, ac1 = 0.f, ac2 = 0.f, ac3 = 0.f;
        #pragma unroll 4
        for (int kk = kst; kk < ken; kk += 4) {
          float4 z = *(const float4*)(zs + kk);
          ac0 += dot4(z, *(const float4*)(base + kk));
          ac1 += dot4(z, *(const float4*)(base + HID + kk));
          ac2 += dot4(z, *(const float4*)(base + 2 * HID + kk));
          ac3 += dot4(z, *(const float4*)(base + 3 * HID + kk));
        }
        part[ks][rem][0] = ac0; part[ks][rem][1] = ac1;
        part[ks][rem][2] = ac2; part[ks][rem][3] = ac3;
      }
      __syncthreads();
      const float4* t4 = (const float4*)(h1b + p * (NAG * HID));
      for (int i4 = tid; i4 < (NAG * HID) / 4; i4 += NTHR) {
        int a = i4 >> 8, k4 = i4 & 255;
        *(float4*)&lds_h[a * 1028 + k4 * 4] = t4[i4];
      }
      __syncthreads();
      if (kact) {
        const size_t nb = (size_t)(krg * HID + b * 4);
        const float* base = P.W_hh1 + nb * HID;
        const float* zs = lds_h + ka * 1028;
        float ac0 = 0.f, ac1 = 0.f, ac2 = 0.f, ac3 = 0.f;
        #pragma unroll 4
        for (int kk = kst; kk < ken; kk += 4) {
          float4 z = *(const float4*)(zs + kk);
          ac0 += dot4(z, *(const float4*)(base + kk));
          ac1 += dot4(z, *(const float4*)(base + HID + kk));
          ac2 += dot4(z, *(const float4*)(base + 2 * HID + kk));
          ac3 += dot4(z, *(const float4*)(base + 3 * HID + kk));
        }
        part[3 + ks][rem][0] = ac0; part[3 + ks][rem][1] = ac1;
        part[3 + ks][rem][2] = ac2; part[3 + ks][rem][3] = ac3;
      }
      __syncthreads();
      if (tid < 84) {
        float g4[4];
        #pragma unroll
        for (int g = 0; g < 4; ++g) {
          int n = g * HID + b * 4 + fh;
          float v = P.b_ih1[n] + P.b_hh1[n];
          #pragma unroll
          for (int s = 0; s < 6; ++s) v += part[s][g * 21 + fa][fh];
          g4[g] = v;
        }
        int idx = fa * HID + b * 4 + fh;
        float si = sigf(g4[0]), sf = sigf(g4[1]), so = sigf(g4[3]);
        float cn = sf * c1[idx] + si * tanhf(g4[2]);
        float hn = so * tanhf(cn);
        c1[idx] = cn;
        h1b[(p ^ 1) * (NAG * HID) + idx] = hn;
      }
    }
    ++ep; grid_barrier(bars, ep, b);
  }

  // ---------- epilogue: out[S-1] + final hidden/cell states ----------
  if (b == 0) {
    const float4* h4 = (const float4*)h1b;   // final h1 is buffer 0 (S even)
    const float4* wo4 = (const float4*)P.W_out;
    float a2 = 0.f;
    for (int j = tid; j < (NAG * HID) / 4; j += NTHR) a2 += dot4(h4[j], wo4[j]);
    a2 = block_sum(a2, red);
    if (tid == 0) P.out[SEQ - 1] = a2 + P.b_out[0];
  }
  const int base = b * 336;
  for (int i = tid; i < 336; i += NTHR) {
    int g = base + i;
    float v;
    if (g < NAG * HID)            v = h0b[g];                 // h0 final (buf 0)
    else if (g < 2 * NAG * HID)   v = h1b[g - NAG * HID];     // h1 final (buf 0)
    else if (g < 3 * NAG * HID)   v = c0[g - 2 * NAG * HID];
    else                          v = c1[g - 3 * NAG * HID];
    P.out[SEQ + g] = v;
  }
}

extern "C" void kernel_launch(void* const* d_in, const int* in_sizes, int n_in,
                              void* d_out, int out_size, void* d_ws, size_t ws_size,
                              hipStream_t stream) {
  (void)in_sizes; (void)n_in; (void)out_size; (void)ws_size;
  Params P;
  P.x     = (const float*)d_in[0];
  P.W_ie  = (const float*)d_in[1];
  P.b_ie  = (const float*)d_in[2];
  P.W_te  = (const float*)d_in[3];
  P.b_te  = (const float*)d_in[4];
  P.W_ih0 = (const float*)d_in[5];
  P.W_hh0 = (const float*)d_in[6];
  P.b_ih0 = (const float*)d_in[7];
  P.b_hh0 = (const float*)d_in[8];
  P.W_ih1 = (const float*)d_in[9];
  P.W_hh1 = (const float*)d_in[10];
  P.b_ih1 = (const float*)d_in[11];
  P.b_hh1 = (const float*)d_in[12];
  P.W_out = (const float*)d_in[13];
  P.b_out = (const float*)d_in[14];
  P.out   = (float*)d_out;
  P.ws    = (float*)d_ws;

  sl_init<<<64, NTHR, 0, stream>>>((float*)d_ws);
  sl_ie<<<SEQ, NTHR, 0, stream>>>(P.x, P.W_ie, P.b_ie, (float*)d_ws);

  void* args[] = { &P };
  hipLaunchCooperativeKernel((const void*)sl_main, dim3(NBLK), dim3(NTHR),
                             args, 0, stream);
}

// Round 6
// 102167.249 us; speedup vs baseline: 1.1633x; 1.1633x over previous
//
#include <hip/hip_runtime.h>
#include <math.h>

// SocialLSTM round 6 (= round-5 design + timeout-abort barrier insurance).
// Register-resident fp32 weights at 512 thr/block: per-thread slice 212
// floats fits under the 256-VGPR cap of __launch_bounds__(512,2) -> inside
// the R1-proven cooperative envelope (<=256 VGPR, <=146KB LDS, coop launch).
// R3 evidence: coop launch silently rejects >256-VGPR kernels (clean no-run).
// R2/R4/R5 "container deaths" are broker reconnects to one dead container
// (same name, "closed while sending first message") - kernel never ran.
// Insurance: grid barrier has a bounded spin (~0.5s) + global abort flag so
// ANY co-residency/sync failure ends as a clean wrong-answer, never a hang.

#define NBLK 256
#define NTHR 512
#define HTHR 256
#define SEQ  1024
#define HID  1024
#define EMB  512
#define NAG  21
#define NH   21504   // NAG*HID

// ws float offsets
#define IE_OFF  0
#define H0_OFF  11010048                   // SEQ*NAG*EMB
#define H1_OFF  (H0_OFF + 2*NH)
#define TE_OFF  (H1_OFF + 2*NH)
#define BAR_OFF (TE_OFF + 512)
#define ZTOT    (4*NH + 512 + 512)

// LDS float offsets (padded: 128-float chunk occupies 132 floats)
#define OFF_H    0          // 21 x 1056
#define OFF_IE   22176      // 21 x 528
#define OFF_TE   33264      // 528
#define OFF_PART 33792      // 21 x 16 x 8 = 2688
#define OFF_B0   36480      // 16
#define OFF_B1   36496      // 16
#define OFF_RED  36512      // 8
#define OFF_ABT  36520      // 1
#define LDS_F    36544      // 146,176 B -> 1 block/CU

struct Params {
  const float *x, *W_ie, *b_ie, *W_te, *b_te;
  const float *W_ih0, *W_hh0, *b_ih0, *b_hh0;
  const float *W_ih1, *W_hh1, *b_ih1, *b_hh1;
  const float *W_out, *b_out;
  float *out, *ws;
};

__device__ __forceinline__ float sigf(float v) { return 1.0f / (1.0f + expf(-v)); }

__device__ __forceinline__ float block_sum(float v, float* red) {
  #pragma unroll
  for (int off = 32; off > 0; off >>= 1) v += __shfl_down(v, off, 64);
  const int w = threadIdx.x >> 6;
  if ((threadIdx.x & 63) == 0) red[w] = v;
  __syncthreads();
  float r = 0.f;
  #pragma unroll
  for (int i = 0; i < NTHR / 64; ++i) r += red[i];
  __syncthreads();
  return r;
}

// 2-level tree barrier (R1-proven) + bounded-spin abort insurance.
// bars[0]=generation; bars[16+g*16]=group-g counter; bars[272]=root;
// bars[300]=global abort flag. Returns true if the grid is aborting.
__device__ __forceinline__ bool grid_barrier(unsigned* bars, unsigned ep, int b,
                                             float* ldsf) {
  __syncthreads();
  if (threadIdx.x == 0) {
    float abortv = 0.f;
    if (__hip_atomic_load(bars + 300, __ATOMIC_RELAXED, __HIP_MEMORY_SCOPE_AGENT) != 0u) {
      abortv = 1.f;
    } else {
      __threadfence();   // release this block's phase writes
      unsigned* gc = bars + 16 + ((unsigned)b >> 4) * 16;
      unsigned old = __hip_atomic_fetch_add(gc, 1u, __ATOMIC_RELAXED, __HIP_MEMORY_SCOPE_AGENT);
      if (old == ep * 16u - 1u) {
        unsigned rold = __hip_atomic_fetch_add(bars + 16 + 256, 1u, __ATOMIC_RELAXED, __HIP_MEMORY_SCOPE_AGENT);
        if (rold == ep * 16u - 1u)
          __hip_atomic_store(bars, ep, __ATOMIC_RELEASE, __HIP_MEMORY_SCOPE_AGENT);
      }
      unsigned spins = 0u;
      while (__hip_atomic_load(bars, __ATOMIC_RELAXED, __HIP_MEMORY_SCOPE_AGENT) < ep) {
        __builtin_amdgcn_s_sleep(8);
        if (++spins > 2000000u) {            // ~0.5s: declare failure, abort grid
          __hip_atomic_store(bars + 300, 1u, __ATOMIC_RELAXED, __HIP_MEMORY_SCOPE_AGENT);
          abortv = 1.f;
          break;
        }
        if ((spins & 1023u) == 0u &&
            __hip_atomic_load(bars + 300, __ATOMIC_RELAXED, __HIP_MEMORY_SCOPE_AGENT) != 0u) {
          abortv = 1.f;
          break;
        }
      }
      __threadfence();   // acquire remote phase writes
    }
    ldsf[OFF_ABT] = abortv;
  }
  __syncthreads();
  return ldsf[OFF_ABT] != 0.f;
}

__global__ void sl_init(float* ws) {
  int tid = blockIdx.x * blockDim.x + threadIdx.x;
  int stride = gridDim.x * blockDim.x;
  for (int i = tid; i < ZTOT; i += stride) ws[H0_OFF + i] = 0.0f;
}

// ie[t,a,e] = relu( sum_{k<43} x[t,k]*W_ie[e,k] + x[t,43+a]*W_ie[e,43] + b_ie[e] )
__global__ void sl_ie(const float* __restrict__ x, const float* __restrict__ W_ie,
                      const float* __restrict__ b_ie, float* __restrict__ ws) {
  const int t = blockIdx.x;
  const int tid = threadIdx.x;
  __shared__ float xs[64];
  __shared__ float base[EMB];
  __shared__ float w43[EMB];
  if (tid < 64) xs[tid] = x[t * 64 + tid];
  __syncthreads();
  for (int e = tid; e < EMB; e += HTHR) {
    const float* wr = W_ie + e * 44;
    float acc = b_ie[e];
    #pragma unroll
    for (int k = 0; k < 43; ++k) acc += xs[k] * wr[k];
    base[e] = acc;
    w43[e] = wr[43];
  }
  __syncthreads();
  float* iep = ws + IE_OFF + (size_t)t * (NAG * EMB);
  for (int idx = tid; idx < NAG * EMB; idx += HTHR) {
    int a = idx >> 9, e = idx & 511;
    float v = base[e] + xs[43 + a] * w43[e];
    iep[idx] = v > 0.0f ? v : 0.0f;
  }
}

__global__ void __launch_bounds__(NTHR, 2) sl_main(Params P) {
  const int b = blockIdx.x;
  const int tid = threadIdx.x;
  float* ws = P.ws;
  float* wste = ws + TE_OFF;
  unsigned* bars = (unsigned*)(ws + BAR_OFF);

  __shared__ float lds[LDS_F];

  const int lane = tid & 63;
  const int wav  = tid >> 6;    // 0..7
  const int n    = tid & 15;    // gate-row-in-16 (gate = n>>2, col j = n&3)
  const int ks   = tid >> 4;    // 0..31 K-slice
  const int grow = (n >> 2) * HID + 4 * b + (n & 3);

  // ---- one-time weight loads into registers (212 floats/thread) ----
  float w0[64];   // layer-0 combined row [W_ih0 | W_hh0], 64-float slice 64*ks
  {
    const float* s0 = (ks < 16) ? (P.W_ih0 + (size_t)grow * 1024 + 64 * ks)
                                : (P.W_hh0 + (size_t)grow * 1024 + 64 * (ks - 16));
    #pragma unroll
    for (int i4 = 0; i4 < 16; ++i4) {
      float4 v = *(const float4*)(s0 + 4 * i4);
      w0[4*i4] = v.x; w0[4*i4+1] = v.y; w0[4*i4+2] = v.z; w0[4*i4+3] = v.w;
      if ((i4 & 3) == 3) __builtin_amdgcn_sched_barrier(0);
    }
  }
  // layer-1: permuted 32-float slice sC so per-wave LDS reads hit distinct banks
  const int sC = ((ks & 3) << 3) | (ks >> 2);
  float w1a[32], w1b[32];
  {
    const float* s1 = P.W_ih1 + (size_t)grow * 1024 + 32 * sC;
    const float* s2 = P.W_hh1 + (size_t)grow * 1024 + 32 * sC;
    #pragma unroll
    for (int i4 = 0; i4 < 8; ++i4) {
      float4 v = *(const float4*)(s1 + 4 * i4);
      w1a[4*i4] = v.x; w1a[4*i4+1] = v.y; w1a[4*i4+2] = v.z; w1a[4*i4+3] = v.w;
      float4 u = *(const float4*)(s2 + 4 * i4);
      w1b[4*i4] = u.x; w1b[4*i4+1] = u.y; w1b[4*i4+2] = u.z; w1b[4*i4+3] = u.w;
      if ((i4 & 3) == 3) __builtin_amdgcn_sched_barrier(0);
    }
  }
  float wte[84];  // W_te rows {2b,2b+1}, strided slice: wte[i] = row[512*i+tid]
  {
    const float* wt0 = P.W_te + (size_t)(2 * b) * NH;
    #pragma unroll
    for (int i = 0; i < 42; ++i) {
      wte[i] = wt0[512 * i + tid];
      if ((i & 7) == 7) __builtin_amdgcn_sched_barrier(0);
    }
    #pragma unroll
    for (int i = 0; i < 42; ++i) {
      wte[42 + i] = wt0[NH + 512 * i + tid];
      if ((i & 7) == 7) __builtin_amdgcn_sched_barrier(0);
    }
  }
  const float bte0 = P.b_te[2 * b], bte1 = P.b_te[2 * b + 1];
  const float bout = P.b_out[0];
  if (tid < 16) {
    int gr = (tid >> 2) * HID + 4 * b + (tid & 3);
    lds[OFF_B0 + tid] = P.b_ih0[gr] + P.b_hh0[gr];
    lds[OFF_B1 + tid] = P.b_ih1[gr] + P.b_hh1[gr];
  }
  __syncthreads();

  // phase-B LDS base: K layout [ie 512 | te 512 | h0 1024], 64-float slices
  int bOffB, aStepB;
  if (ks < 8)       { int s = ks;      bOffB = OFF_IE + 132*(s>>1) + 64*(s&1); aStepB = 528;  }
  else if (ks < 16) { int s = ks - 8;  bOffB = OFF_TE + 132*(s>>1) + 64*(s&1); aStepB = 0;    }
  else              { int s = ks - 16; bOffB = OFF_H  + 132*(s>>1) + 64*(s&1); aStepB = 1056; }
  const int bOffC = OFF_H + 132 * (sC >> 2) + 32 * (sC & 3);

  // persistent per-thread state (threads tid<84 own cell (a = tid>>2, j = tid&3))
  float c0r = 0.f, c1r = 0.f, h0r = 0.f, h1r = 0.f;
  unsigned ep = 0;

  for (int t = 0; t < SEQ; ++t) {
    const int p = t & 1;

    // ---------- phase A: te rows {2b,2b+1}; block0: out[t-1] ----------
    {
      const float* h1s = ws + H1_OFF + p * NH;
      float a0 = 0.f, a1 = 0.f;
      #pragma unroll 6
      for (int i = 0; i < 42; ++i) {
        float hv = h1s[512 * i + tid];
        a0 += wte[i] * hv;
        a1 += wte[42 + i] * hv;
      }
      a0 = block_sum(a0, &lds[OFF_RED]);
      a1 = block_sum(a1, &lds[OFF_RED]);
      if (tid == 0) {
        float v0 = a0 + bte0, v1 = a1 + bte1;
        wste[2*b]   = v0 > 0.f ? v0 : 0.f;
        wste[2*b+1] = v1 > 0.f ? v1 : 0.f;
      }
      if (b == 0) {
        float ao = 0.f;
        if (t > 0) {
          #pragma unroll 6
          for (int i = 0; i < 42; ++i)
            ao += P.W_out[512 * i + tid] * h1s[512 * i + tid];
        }
        ao = block_sum(ao, &lds[OFF_RED]);
        if (tid == 0 && t > 0) P.out[t - 1] = ao + bout;
      }
    }
    ++ep; if (grid_barrier(bars, ep, b, lds)) break;

    // ---------- phase B: layer-0 ----------
    {
      const float* h0p = ws + H0_OFF + p * NH;
      for (int i = tid; i < 5376; i += NTHR) {       // stage h0p (21x1024)
        int a = i >> 8, k4 = i & 255;
        float4 v = *(const float4*)(h0p + 4 * i);
        *(float4*)&lds[OFF_H + a*1056 + 132*(k4>>5) + 4*(k4&31)] = v;
      }
      const float* iep = ws + IE_OFF + (size_t)t * (NAG * EMB);
      for (int i = tid; i < 2688; i += NTHR) {       // stage ie[t] (21x512)
        int a = i >> 7, k4 = i & 127;
        float4 v = *(const float4*)(iep + 4 * i);
        *(float4*)&lds[OFF_IE + a*528 + 132*(k4>>5) + 4*(k4&31)] = v;
      }
      if (tid < 128) {                               // stage te (512)
        float4 v = *(const float4*)(wste + 4 * tid);
        *(float4*)&lds[OFF_TE + 132*(tid>>5) + 4*(tid&31)] = v;
      }
      __syncthreads();
      int laddr = bOffB;
      for (int a = 0; a < NAG; ++a) {
        float ac0 = 0.f, ac1 = 0.f, ac2 = 0.f, ac3 = 0.f;
        #pragma unroll
        for (int i4 = 0; i4 < 16; ++i4) {
          float4 z = *(const float4*)&lds[laddr + 4 * i4];
          if ((i4 & 3) == 0) { ac0 += w0[4*i4]*z.x; ac0 += w0[4*i4+1]*z.y; ac0 += w0[4*i4+2]*z.z; ac0 += w0[4*i4+3]*z.w; }
          if ((i4 & 3) == 1) { ac1 += w0[4*i4]*z.x; ac1 += w0[4*i4+1]*z.y; ac1 += w0[4*i4+2]*z.z; ac1 += w0[4*i4+3]*z.w; }
          if ((i4 & 3) == 2) { ac2 += w0[4*i4]*z.x; ac2 += w0[4*i4+1]*z.y; ac2 += w0[4*i4+2]*z.z; ac2 += w0[4*i4+3]*z.w; }
          if ((i4 & 3) == 3) { ac3 += w0[4*i4]*z.x; ac3 += w0[4*i4+1]*z.y; ac3 += w0[4*i4+2]*z.z; ac3 += w0[4*i4+3]*z.w; }
        }
        float acc = (ac0 + ac1) + (ac2 + ac3);
        acc += __shfl_xor(acc, 16);
        acc += __shfl_xor(acc, 32);
        if (lane < 16) lds[OFF_PART + a*128 + n*8 + wav] = acc;
        laddr += aStepB;
      }
      __syncthreads();
      if (tid < 84) {
        int a = tid >> 2, j = tid & 3;
        const float* pp = &lds[OFF_PART + a * 128];
        float g[4];
        #pragma unroll
        for (int gg = 0; gg < 4; ++gg) {
          float s = lds[OFF_B0 + gg * 4 + j];
          #pragma unroll
          for (int w = 0; w < 8; ++w) s += pp[(gg * 4 + j) * 8 + w];
          g[gg] = s;
        }
        float cn = sigf(g[1]) * c0r + sigf(g[0]) * tanhf(g[2]);
        float hn = sigf(g[3]) * tanhf(cn);
        c0r = cn; h0r = hn;
        ws[H0_OFF + (p ^ 1) * NH + a * HID + 4 * b + j] = hn;
      }
    }
    ++ep; if (grid_barrier(bars, ep, b, lds)) break;

    // ---------- phase C: layer-1 (pass1: h0n x W_ih1; pass2: h1p x W_hh1) ----------
    {
      const float* h0n = ws + H0_OFF + (p ^ 1) * NH;
      for (int i = tid; i < 5376; i += NTHR) {
        int a = i >> 8, k4 = i & 255;
        float4 v = *(const float4*)(h0n + 4 * i);
        *(float4*)&lds[OFF_H + a*1056 + 132*(k4>>5) + 4*(k4&31)] = v;
      }
      __syncthreads();
      int laddr = bOffC;
      for (int a = 0; a < NAG; ++a) {
        float ac0 = 0.f, ac1 = 0.f;
        #pragma unroll
        for (int i4 = 0; i4 < 8; ++i4) {
          float4 z = *(const float4*)&lds[laddr + 4 * i4];
          if ((i4 & 1) == 0) { ac0 += w1a[4*i4]*z.x; ac0 += w1a[4*i4+1]*z.y; ac0 += w1a[4*i4+2]*z.z; ac0 += w1a[4*i4+3]*z.w; }
          if ((i4 & 1) == 1) { ac1 += w1a[4*i4]*z.x; ac1 += w1a[4*i4+1]*z.y; ac1 += w1a[4*i4+2]*z.z; ac1 += w1a[4*i4+3]*z.w; }
        }
        float acc = ac0 + ac1;
        acc += __shfl_xor(acc, 16);
        acc += __shfl_xor(acc, 32);
        if (lane < 16) lds[OFF_PART + a*128 + n*8 + wav] = acc;
        laddr += 1056;
      }
      __syncthreads();
      const float* h1pp = ws + H1_OFF + p * NH;
      for (int i = tid; i < 5376; i += NTHR) {
        int a = i >> 8, k4 = i & 255;
        float4 v = *(const float4*)(h1pp + 4 * i);
        *(float4*)&lds[OFF_H + a*1056 + 132*(k4>>5) + 4*(k4&31)] = v;
      }
      __syncthreads();
      laddr = bOffC;
      for (int a = 0; a < NAG; ++a) {
        float ac0 = 0.f, ac1 = 0.f;
        #pragma unroll
        for (int i4 = 0; i4 < 8; ++i4) {
          float4 z = *(const float4*)&lds[laddr + 4 * i4];
          if ((i4 & 1) == 0) { ac0 += w1b[4*i4]*z.x; ac0 += w1b[4*i4+1]*z.y; ac0 += w1b[4*i4+2]*z.z; ac0 += w1b[4*i4+3]*z.w; }
          if ((i4 & 1) == 1) { ac1 += w1b[4*i4]*z.x; ac1 += w1b[4*i4+1]*z.y; ac1 += w1b[4*i4+2]*z.z; ac1 += w1b[4*i4+3]*z.w; }
        }
        float acc = ac0 + ac1;
        acc += __shfl_xor(acc, 16);
        acc += __shfl_xor(acc, 32);
        if (lane < 16) lds[OFF_PART + a*128 + n*8 + wav] += acc;
        laddr += 1056;
      }
      __syncthreads();
      if (tid < 84) {
        int a = tid >> 2, j = tid & 3;
        const float* pp = &lds[OFF_PART + a * 128];
        float g[4];
        #pragma unroll
        for (int gg = 0; gg < 4; ++gg) {
          float s = lds[OFF_B1 + gg * 4 + j];
          #pragma unroll
          for (int w = 0; w < 8; ++w) s += pp[(gg * 4 + j) * 8 + w];
          g[gg] = s;
        }
        float cn = sigf(g[1]) * c1r + sigf(g[0]) * tanhf(g[2]);
        float hn = sigf(g[3]) * tanhf(cn);
        c1r = cn; h1r = hn;
        ws[H1_OFF + (p ^ 1) * NH + a * HID + 4 * b + j] = hn;
      }
    }
    ++ep; if (grid_barrier(bars, ep, b, lds)) break;
  }

  // ---------- epilogue: out[S-1] + final states from registers ----------
  if (b == 0) {
    const float* h1s = ws + H1_OFF;   // final h1 in buffer 0 (S even)
    float ao = 0.f;
    #pragma unroll 6
    for (int i = 0; i < 42; ++i)
      ao += P.W_out[512 * i + tid] * h1s[512 * i + tid];
    ao = block_sum(ao, &lds[OFF_RED]);
    if (tid == 0) P.out[SEQ - 1] = ao + bout;
  }
  if (tid < 84) {
    int a = tid >> 2, j = tid & 3;
    int idx = a * HID + 4 * b + j;
    P.out[SEQ + idx]          = h0r;
    P.out[SEQ + NH + idx]     = h1r;
    P.out[SEQ + 2*NH + idx]   = c0r;
    P.out[SEQ + 3*NH + idx]   = c1r;
  }
}

extern "C" void kernel_launch(void* const* d_in, const int* in_sizes, int n_in,
                              void* d_out, int out_size, void* d_ws, size_t ws_size,
                              hipStream_t stream) {
  (void)in_sizes; (void)n_in; (void)out_size; (void)ws_size;
  Params P;
  P.x     = (const float*)d_in[0];
  P.W_ie  = (const float*)d_in[1];
  P.b_ie  = (const float*)d_in[2];
  P.W_te  = (const float*)d_in[3];
  P.b_te  = (const float*)d_in[4];
  P.W_ih0 = (const float*)d_in[5];
  P.W_hh0 = (const float*)d_in[6];
  P.b_ih0 = (const float*)d_in[7];
  P.b_hh0 = (const float*)d_in[8];
  P.W_ih1 = (const float*)d_in[9];
  P.W_hh1 = (const float*)d_in[10];
  P.b_ih1 = (const float*)d_in[11];
  P.b_hh1 = (const float*)d_in[12];
  P.W_out = (const float*)d_in[13];
  P.b_out = (const float*)d_in[14];
  P.out   = (float*)d_out;
  P.ws    = (float*)d_ws;

  sl_init<<<64, HTHR, 0, stream>>>((float*)d_ws);
  sl_ie<<<SEQ, HTHR, 0, stream>>>(P.x, P.W_ie, P.b_ie, (float*)d_ws);

  void* args[] = { &P };
  hipLaunchCooperativeKernel((const void*)sl_main, dim3(NBLK), dim3(NTHR),
                             args, 0, stream);
}

// Round 8
// 82592.181 us; speedup vs baseline: 1.4390x; 1.2370x over previous
//
#include <hip/hip_runtime.h>
#include <math.h>

// SocialLSTM round 8 (= round 7 resubmitted; dead-container infra failure,
// kernel never ran). Fence-free grid barrier + conflict-free LDS chunking.
// R6 evidence: 100us/step pure stall with VALU 12%/HBM 2%/LDS idle, invariant
// across two very different compute structures; attributed to the 2x
// __threadfence() (= whole-L2 writeback/invalidate on gfx950) around each of
// the 3 grid barriers per step. This round: cross-block data moves via
// relaxed AGENT-scope atomic loads/stores (write-through / cache-bypass, no
// L2 flush); barrier = relaxed tree atomics only (+ compiler memory fence).
// __syncthreads drains vmcnt before s_barrier (m97 asm), giving ordering.
// LDS: 32-float chunks @ stride 36 -> the 4 broadcast addrs/wave hit
// disjoint bank quads (R6 had 6.2e9 conflict cycles from 64-float strides).

#define NBLK 256
#define NTHR 512
#define HTHR 256
#define SEQ  1024
#define HID  1024
#define EMB  512
#define NAG  21
#define NH   21504   // NAG*HID

// ws float offsets
#define IE_OFF  0
#define H0_OFF  11010048                   // SEQ*NAG*EMB
#define H1_OFF  (H0_OFF + 2*NH)
#define TE_OFF  (H1_OFF + 2*NH)
#define BAR_OFF (TE_OFF + 512)
#define ZTOT    (4*NH + 512 + 512)

// LDS float offsets. Activations in 32-float chunks at stride 36.
#define HROW   1152                        // 32 chunks * 36
#define IEROW  576                         // 16 chunks * 36
#define OFF_H    0                         // 21 * 1152 = 24192
#define OFF_IE   24192                     // 21 * 576  = 12096
#define OFF_TE   36288                     // 576
#define OFF_PART 36864                     // 21 * 144 (stride 9 per row-entry)
#define OFF_B0   39888                     // 16
#define OFF_B1   39904                     // 16
#define OFF_RED  39920                     // 8
#define OFF_ABT  39928                     // 1
#define LDS_F    39936                     // 159,744 B -> 1 block/CU

struct Params {
  const float *x, *W_ie, *b_ie, *W_te, *b_te;
  const float *W_ih0, *W_hh0, *b_ih0, *b_hh0;
  const float *W_ih1, *W_hh1, *b_ih1, *b_hh1;
  const float *W_out, *b_out;
  float *out, *ws;
};

__device__ __forceinline__ float sigf(float v) { return 1.0f / (1.0f + expf(-v)); }

__device__ __forceinline__ float ald(const float* p) {
  return __hip_atomic_load(p, __ATOMIC_RELAXED, __HIP_MEMORY_SCOPE_AGENT);
}
__device__ __forceinline__ void ast(float* p, float v) {
  __hip_atomic_store(p, v, __ATOMIC_RELAXED, __HIP_MEMORY_SCOPE_AGENT);
}

__device__ __forceinline__ float block_sum(float v, float* red) {
  #pragma unroll
  for (int off = 32; off > 0; off >>= 1) v += __shfl_down(v, off, 64);
  const int w = threadIdx.x >> 6;
  if ((threadIdx.x & 63) == 0) red[w] = v;
  __syncthreads();
  float r = 0.f;
  #pragma unroll
  for (int i = 0; i < NTHR / 64; ++i) r += red[i];
  __syncthreads();
  return r;
}

// Fence-free 2-level tree barrier. bars[0]=generation; bars[16+g*16]=group
// counter; bars[272]=root; bars[300]=abort flag. All accesses are relaxed
// AGENT-scope atomics (coherence-point serialized); no L2 flush/invalidate.
__device__ __forceinline__ bool grid_barrier(unsigned* bars, unsigned ep, int b,
                                             float* ldsf) {
  __syncthreads();
  if (threadIdx.x == 0) {
    float abortv = 0.f;
    if (__hip_atomic_load(bars + 300, __ATOMIC_RELAXED, __HIP_MEMORY_SCOPE_AGENT) != 0u) {
      abortv = 1.f;
    } else {
      asm volatile("s_waitcnt vmcnt(0)" ::: "memory");
      unsigned* gc = bars + 16 + ((unsigned)b >> 4) * 16;
      unsigned old = __hip_atomic_fetch_add(gc, 1u, __ATOMIC_RELAXED, __HIP_MEMORY_SCOPE_AGENT);
      if (old == ep * 16u - 1u) {
        unsigned rold = __hip_atomic_fetch_add(bars + 16 + 256, 1u, __ATOMIC_RELAXED, __HIP_MEMORY_SCOPE_AGENT);
        if (rold == ep * 16u - 1u)
          __hip_atomic_store(bars, ep, __ATOMIC_RELAXED, __HIP_MEMORY_SCOPE_AGENT);
      }
      unsigned spins = 0u;
      while (__hip_atomic_load(bars, __ATOMIC_RELAXED, __HIP_MEMORY_SCOPE_AGENT) < ep) {
        __builtin_amdgcn_s_sleep(1);
        if (++spins > 30000000u) {           // ~1s: declare failure, abort grid
          __hip_atomic_store(bars + 300, 1u, __ATOMIC_RELAXED, __HIP_MEMORY_SCOPE_AGENT);
          abortv = 1.f;
          break;
        }
        if ((spins & 2047u) == 0u &&
            __hip_atomic_load(bars + 300, __ATOMIC_RELAXED, __HIP_MEMORY_SCOPE_AGENT) != 0u) {
          abortv = 1.f;
          break;
        }
      }
      asm volatile("" ::: "memory");   // compiler-only fence: no hoisting of data reads
    }
    ldsf[OFF_ABT] = abortv;
  }
  __syncthreads();
  return ldsf[OFF_ABT] != 0.f;
}

__global__ void sl_init(float* ws) {
  int tid = blockIdx.x * blockDim.x + threadIdx.x;
  int stride = gridDim.x * blockDim.x;
  for (int i = tid; i < ZTOT; i += stride) ws[H0_OFF + i] = 0.0f;
}

// ie[t,a,e] = relu( sum_{k<43} x[t,k]*W_ie[e,k] + x[t,43+a]*W_ie[e,43] + b_ie[e] )
__global__ void sl_ie(const float* __restrict__ x, const float* __restrict__ W_ie,
                      const float* __restrict__ b_ie, float* __restrict__ ws) {
  const int t = blockIdx.x;
  const int tid = threadIdx.x;
  __shared__ float xs[64];
  __shared__ float base[EMB];
  __shared__ float w43[EMB];
  if (tid < 64) xs[tid] = x[t * 64 + tid];
  __syncthreads();
  for (int e = tid; e < EMB; e += HTHR) {
    const float* wr = W_ie + e * 44;
    float acc = b_ie[e];
    #pragma unroll
    for (int k = 0; k < 43; ++k) acc += xs[k] * wr[k];
    base[e] = acc;
    w43[e] = wr[43];
  }
  __syncthreads();
  float* iep = ws + IE_OFF + (size_t)t * (NAG * EMB);
  for (int idx = tid; idx < NAG * EMB; idx += HTHR) {
    int a = idx >> 9, e = idx & 511;
    float v = base[e] + xs[43 + a] * w43[e];
    iep[idx] = v > 0.0f ? v : 0.0f;
  }
}

__global__ void __launch_bounds__(NTHR, 2) sl_main(Params P) {
  const int b = blockIdx.x;
  const int tid = threadIdx.x;
  float* ws = P.ws;
  float* wste = ws + TE_OFF;
  unsigned* bars = (unsigned*)(ws + BAR_OFF);

  __shared__ float lds[LDS_F];

  const int lane = tid & 63;
  const int wav  = tid >> 6;    // 0..7
  const int n    = tid & 15;    // gate-row-in-16 (gate = n>>2, col j = n&3)
  const int ks   = tid >> 4;    // 0..31 K-slice
  const int grow = (n >> 2) * HID + 4 * b + (n & 3);

  // ---- one-time weight loads into registers (212 floats/thread) ----
  float w0[64];   // layer-0 combined row [W_ih0 | W_hh0], 64-float slice 64*ks
  {
    const float* s0 = (ks < 16) ? (P.W_ih0 + (size_t)grow * 1024 + 64 * ks)
                                : (P.W_hh0 + (size_t)grow * 1024 + 64 * (ks - 16));
    #pragma unroll
    for (int i4 = 0; i4 < 16; ++i4) {
      float4 v = *(const float4*)(s0 + 4 * i4);
      w0[4*i4] = v.x; w0[4*i4+1] = v.y; w0[4*i4+2] = v.z; w0[4*i4+3] = v.w;
      if ((i4 & 3) == 3) __builtin_amdgcn_sched_barrier(0);
    }
  }
  float w1a[32], w1b[32];   // layer-1 rows, natural 32-float slice 32*ks
  {
    const float* s1 = P.W_ih1 + (size_t)grow * 1024 + 32 * ks;
    const float* s2 = P.W_hh1 + (size_t)grow * 1024 + 32 * ks;
    #pragma unroll
    for (int i4 = 0; i4 < 8; ++i4) {
      float4 v = *(const float4*)(s1 + 4 * i4);
      w1a[4*i4] = v.x; w1a[4*i4+1] = v.y; w1a[4*i4+2] = v.z; w1a[4*i4+3] = v.w;
      float4 u = *(const float4*)(s2 + 4 * i4);
      w1b[4*i4] = u.x; w1b[4*i4+1] = u.y; w1b[4*i4+2] = u.z; w1b[4*i4+3] = u.w;
      if ((i4 & 3) == 3) __builtin_amdgcn_sched_barrier(0);
    }
  }
  float wte[84];  // W_te rows {2b,2b+1}, strided slice: wte[i] = row[512*i+tid]
  {
    const float* wt0 = P.W_te + (size_t)(2 * b) * NH;
    #pragma unroll
    for (int i = 0; i < 42; ++i) {
      wte[i] = wt0[512 * i + tid];
      if ((i & 7) == 7) __builtin_amdgcn_sched_barrier(0);
    }
    #pragma unroll
    for (int i = 0; i < 42; ++i) {
      wte[42 + i] = wt0[NH + 512 * i + tid];
      if ((i & 7) == 7) __builtin_amdgcn_sched_barrier(0);
    }
  }
  const float bte0 = P.b_te[2 * b], bte1 = P.b_te[2 * b + 1];
  const float bout = P.b_out[0];
  if (tid < 16) {
    int gr = (tid >> 2) * HID + 4 * b + (tid & 3);
    lds[OFF_B0 + tid] = P.b_ih0[gr] + P.b_hh0[gr];
    lds[OFF_B1 + tid] = P.b_ih1[gr] + P.b_hh1[gr];
  }
  __syncthreads();

  // phase-B LDS base: K = [ie 512 | te 512 | h0 1024] in 64-float slices
  // (2 chunks of 32@36). Wave's 4 slice-bases differ by 72 -> banks {0,8,16,24}.
  int bB_base, bB_astep;
  if (ks < 8)       { bB_base = OFF_IE + 72 * ks;        bB_astep = IEROW; }
  else if (ks < 16) { bB_base = OFF_TE + 72 * (ks - 8);  bB_astep = 0;     }
  else              { bB_base = OFF_H  + 72 * (ks - 16); bB_astep = HROW;  }
  // phase-C base: 32-float slice = chunk ks. Wave's 4 bases differ by 36 ->
  // banks {0,4,8,12}.
  const int bC_base = OFF_H + 36 * ks;

  float c0r = 0.f, c1r = 0.f, h0r = 0.f, h1r = 0.f;
  unsigned ep = 0;

  for (int t = 0; t < SEQ; ++t) {
    const int p = t & 1;

    // ---------- phase A: te rows {2b,2b+1}; block0: out[t-1] ----------
    {
      const float* h1s = ws + H1_OFF + p * NH;
      float a0 = 0.f, a1 = 0.f;
      #pragma unroll 6
      for (int i = 0; i < 42; ++i) {
        float hv = ald(h1s + 512 * i + tid);
        a0 += wte[i] * hv;
        a1 += wte[42 + i] * hv;
      }
      a0 = block_sum(a0, &lds[OFF_RED]);
      a1 = block_sum(a1, &lds[OFF_RED]);
      if (tid == 0) {
        float v0 = a0 + bte0, v1 = a1 + bte1;
        v0 = v0 > 0.f ? v0 : 0.f;
        v1 = v1 > 0.f ? v1 : 0.f;
        unsigned long long tv = ((unsigned long long)__float_as_uint(v1) << 32)
                              | (unsigned long long)__float_as_uint(v0);
        __hip_atomic_store((unsigned long long*)(wste + 2 * b), tv,
                           __ATOMIC_RELAXED, __HIP_MEMORY_SCOPE_AGENT);
      }
      if (b == 0) {
        float ao = 0.f;
        if (t > 0) {
          #pragma unroll 6
          for (int i = 0; i < 42; ++i)
            ao += P.W_out[512 * i + tid] * ald(h1s + 512 * i + tid);
        }
        ao = block_sum(ao, &lds[OFF_RED]);
        if (tid == 0 && t > 0) P.out[t - 1] = ao + bout;
      }
    }
    ++ep; if (grid_barrier(bars, ep, b, lds)) break;

    // ---------- phase B: layer-0 ----------
    {
      // stage h0p (sc-coherent, 2 floats per load)
      const unsigned long long* h0p8 =
          (const unsigned long long*)(ws + H0_OFF + p * NH);
      for (int i2 = tid; i2 < NH / 2; i2 += NTHR) {
        unsigned long long v = __hip_atomic_load(h0p8 + i2, __ATOMIC_RELAXED,
                                                 __HIP_MEMORY_SCOPE_AGENT);
        int idx = i2 * 2, a = idx >> 10, c = idx & 1023;
        float2 f;
        f.x = __uint_as_float((unsigned)(v & 0xffffffffULL));
        f.y = __uint_as_float((unsigned)(v >> 32));
        *(float2*)&lds[OFF_H + a * HROW + 36 * (c >> 5) + (c & 31)] = f;
      }
      // stage ie[t] (read-only data: plain cached float4)
      const float* iep = ws + IE_OFF + (size_t)t * (NAG * EMB);
      for (int i4 = tid; i4 < 2688; i4 += NTHR) {
        int a = i4 >> 7, k4 = i4 & 127;
        float4 v = *(const float4*)(iep + 4 * i4);
        *(float4*)&lds[OFF_IE + a * IEROW + 36 * (k4 >> 3) + 4 * (k4 & 7)] = v;
      }
      // stage te (sc-coherent scalar)
      lds[OFF_TE + 36 * (tid >> 5) + (tid & 31)] = ald(wste + tid);
      __syncthreads();

      int laddr = bB_base;
      for (int a = 0; a < NAG; ++a) {
        float ac0 = 0.f, ac1 = 0.f, ac2 = 0.f, ac3 = 0.f;
        #pragma unroll
        for (int j = 0; j < 8; ++j) {
          float4 z = *(const float4*)&lds[laddr + 4 * j];
          if ((j & 3) == 0) { ac0 += w0[4*j]*z.x; ac0 += w0[4*j+1]*z.y; ac0 += w0[4*j+2]*z.z; ac0 += w0[4*j+3]*z.w; }
          if ((j & 3) == 1) { ac1 += w0[4*j]*z.x; ac1 += w0[4*j+1]*z.y; ac1 += w0[4*j+2]*z.z; ac1 += w0[4*j+3]*z.w; }
          if ((j & 3) == 2) { ac2 += w0[4*j]*z.x; ac2 += w0[4*j+1]*z.y; ac2 += w0[4*j+2]*z.z; ac2 += w0[4*j+3]*z.w; }
          if ((j & 3) == 3) { ac3 += w0[4*j]*z.x; ac3 += w0[4*j+1]*z.y; ac3 += w0[4*j+2]*z.z; ac3 += w0[4*j+3]*z.w; }
        }
        #pragma unroll
        for (int j = 0; j < 8; ++j) {
          float4 z = *(const float4*)&lds[laddr + 36 + 4 * j];
          const float* wp = w0 + 32;
          if ((j & 3) == 0) { ac0 += wp[4*j]*z.x; ac0 += wp[4*j+1]*z.y; ac0 += wp[4*j+2]*z.z; ac0 += wp[4*j+3]*z.w; }
          if ((j & 3) == 1) { ac1 += wp[4*j]*z.x; ac1 += wp[4*j+1]*z.y; ac1 += wp[4*j+2]*z.z; ac1 += wp[4*j+3]*z.w; }
          if ((j & 3) == 2) { ac2 += wp[4*j]*z.x; ac2 += wp[4*j+1]*z.y; ac2 += wp[4*j+2]*z.z; ac2 += wp[4*j+3]*z.w; }
          if ((j & 3) == 3) { ac3 += wp[4*j]*z.x; ac3 += wp[4*j+1]*z.y; ac3 += wp[4*j+2]*z.z; ac3 += wp[4*j+3]*z.w; }
        }
        float acc = (ac0 + ac1) + (ac2 + ac3);
        acc += __shfl_xor(acc, 16);
        acc += __shfl_xor(acc, 32);
        if (lane < 16) lds[OFF_PART + a * 144 + n * 9 + wav] = acc;
        laddr += bB_astep;
      }
      __syncthreads();
      if (tid < 84) {
        int a = tid >> 2, j = tid & 3;
        const float* pp = &lds[OFF_PART + a * 144];
        float g[4];
        #pragma unroll
        for (int gg = 0; gg < 4; ++gg) {
          float s = lds[OFF_B0 + gg * 4 + j];
          #pragma unroll
          for (int w = 0; w < 8; ++w) s += pp[(gg * 4 + j) * 9 + w];
          g[gg] = s;
        }
        float cn = sigf(g[1]) * c0r + sigf(g[0]) * tanhf(g[2]);
        float hn = sigf(g[3]) * tanhf(cn);
        c0r = cn; h0r = hn;
        ast(ws + H0_OFF + (p ^ 1) * NH + a * HID + 4 * b + j, hn);
      }
    }
    ++ep; if (grid_barrier(bars, ep, b, lds)) break;

    // ---------- phase C: layer-1 (pass1: h0n x W_ih1; pass2: h1p x W_hh1) ----------
    {
      const unsigned long long* h0n8 =
          (const unsigned long long*)(ws + H0_OFF + (p ^ 1) * NH);
      for (int i2 = tid; i2 < NH / 2; i2 += NTHR) {
        unsigned long long v = __hip_atomic_load(h0n8 + i2, __ATOMIC_RELAXED,
                                                 __HIP_MEMORY_SCOPE_AGENT);
        int idx = i2 * 2, a = idx >> 10, c = idx & 1023;
        float2 f;
        f.x = __uint_as_float((unsigned)(v & 0xffffffffULL));
        f.y = __uint_as_float((unsigned)(v >> 32));
        *(float2*)&lds[OFF_H + a * HROW + 36 * (c >> 5) + (c & 31)] = f;
      }
      __syncthreads();
      int laddr = bC_base;
      for (int a = 0; a < NAG; ++a) {
        float ac0 = 0.f, ac1 = 0.f;
        #pragma unroll
        for (int j = 0; j < 8; ++j) {
          float4 z = *(const float4*)&lds[laddr + 4 * j];
          if ((j & 1) == 0) { ac0 += w1a[4*j]*z.x; ac0 += w1a[4*j+1]*z.y; ac0 += w1a[4*j+2]*z.z; ac0 += w1a[4*j+3]*z.w; }
          if ((j & 1) == 1) { ac1 += w1a[4*j]*z.x; ac1 += w1a[4*j+1]*z.y; ac1 += w1a[4*j+2]*z.z; ac1 += w1a[4*j+3]*z.w; }
        }
        float acc = ac0 + ac1;
        acc += __shfl_xor(acc, 16);
        acc += __shfl_xor(acc, 32);
        if (lane < 16) lds[OFF_PART + a * 144 + n * 9 + wav] = acc;
        laddr += HROW;
      }
      __syncthreads();
      const unsigned long long* h1p8 =
          (const unsigned long long*)(ws + H1_OFF + p * NH);
      for (int i2 = tid; i2 < NH / 2; i2 += NTHR) {
        unsigned long long v = __hip_atomic_load(h1p8 + i2, __ATOMIC_RELAXED,
                                                 __HIP_MEMORY_SCOPE_AGENT);
        int idx = i2 * 2, a = idx >> 10, c = idx & 1023;
        float2 f;
        f.x = __uint_as_float((unsigned)(v & 0xffffffffULL));
        f.y = __uint_as_float((unsigned)(v >> 32));
        *(float2*)&lds[OFF_H + a * HROW + 36 * (c >> 5) + (c & 31)] = f;
      }
      __syncthreads();
      laddr = bC_base;
      for (int a = 0; a < NAG; ++a) {
        float ac0 = 0.f, ac1 = 0.f;
        #pragma unroll
        for (int j = 0; j < 8; ++j) {
          float4 z = *(const float4*)&lds[laddr + 4 * j];
          if ((j & 1) == 0) { ac0 += w1b[4*j]*z.x; ac0 += w1b[4*j+1]*z.y; ac0 += w1b[4*j+2]*z.z; ac0 += w1b[4*j+3]*z.w; }
          if ((j & 1) == 1) { ac1 += w1b[4*j]*z.x; ac1 += w1b[4*j+1]*z.y; ac1 += w1b[4*j+2]*z.z; ac1 += w1b[4*j+3]*z.w; }
        }
        float acc = ac0 + ac1;
        acc += __shfl_xor(acc, 16);
        acc += __shfl_xor(acc, 32);
        if (lane < 16) lds[OFF_PART + a * 144 + n * 9 + wav] += acc;
        laddr += HROW;
      }
      __syncthreads();
      if (tid < 84) {
        int a = tid >> 2, j = tid & 3;
        const float* pp = &lds[OFF_PART + a * 144];
        float g[4];
        #pragma unroll
        for (int gg = 0; gg < 4; ++gg) {
          float s = lds[OFF_B1 + gg * 4 + j];
          #pragma unroll
          for (int w = 0; w < 8; ++w) s += pp[(gg * 4 + j) * 9 + w];
          g[gg] = s;
        }
        float cn = sigf(g[1]) * c1r + sigf(g[0]) * tanhf(g[2]);
        float hn = sigf(g[3]) * tanhf(cn);
        c1r = cn; h1r = hn;
        ast(ws + H1_OFF + (p ^ 1) * NH + a * HID + 4 * b + j, hn);
      }
    }
    ++ep; if (grid_barrier(bars, ep, b, lds)) break;
  }

  // ---------- epilogue: out[S-1] + final states from registers ----------
  if (b == 0) {
    const float* h1s = ws + H1_OFF;   // final h1 in buffer 0 (S even)
    float ao = 0.f;
    #pragma unroll 6
    for (int i = 0; i < 42; ++i)
      ao += P.W_out[512 * i + tid] * ald(h1s + 512 * i + tid);
    ao = block_sum(ao, &lds[OFF_RED]);
    if (tid == 0) P.out[SEQ - 1] = ao + bout;
  }
  if (tid < 84) {
    int a = tid >> 2, j = tid & 3;
    int idx = a * HID + 4 * b + j;
    P.out[SEQ + idx]          = h0r;
    P.out[SEQ + NH + idx]     = h1r;
    P.out[SEQ + 2*NH + idx]   = c0r;
    P.out[SEQ + 3*NH + idx]   = c1r;
  }
}

extern "C" void kernel_launch(void* const* d_in, const int* in_sizes, int n_in,
                              void* d_out, int out_size, void* d_ws, size_t ws_size,
                              hipStream_t stream) {
  (void)in_sizes; (void)n_in; (void)out_size; (void)ws_size;
  Params P;
  P.x     = (const float*)d_in[0];
  P.W_ie  = (const float*)d_in[1];
  P.b_ie  = (const float*)d_in[2];
  P.W_te  = (const float*)d_in[3];
  P.b_te  = (const float*)d_in[4];
  P.W_ih0 = (const float*)d_in[5];
  P.W_hh0 = (const float*)d_in[6];
  P.b_ih0 = (const float*)d_in[7];
  P.b_hh0 = (const float*)d_in[8];
  P.W_ih1 = (const float*)d_in[9];
  P.W_hh1 = (const float*)d_in[10];
  P.b_ih1 = (const float*)d_in[11];
  P.b_hh1 = (const float*)d_in[12];
  P.W_out = (const float*)d_in[13];
  P.b_out = (const float*)d_in[14];
  P.out   = (float*)d_out;
  P.ws    = (float*)d_ws;

  sl_init<<<64, HTHR, 0, stream>>>((float*)d_ws);
  sl_ie<<<SEQ, HTHR, 0, stream>>>(P.x, P.W_ie, P.b_ie, (float*)d_ws);

  void* args[] = { &P };
  hipLaunchCooperativeKernel((const void*)sl_main, dim3(NBLK), dim3(NTHR),
                             args, 0, stream);
}